// Round 7
// baseline (192.983 us; speedup 1.0000x reference)
//
#include <hip/hip_runtime.h>

// Problem constants
#define S_DIM 8192
#define K_DIM 1024
#define RO_DIM 4096
#define O_DIM 64
#define SO (S_DIM * O_DIM)
#define NSLICE 8  // split-N partial slices (rule-loop: 4 N-tiles per block)

typedef __attribute__((ext_vector_type(8))) __bf16 bf16x8;
typedef __attribute__((ext_vector_type(4))) float floatx4;
typedef __attribute__((ext_vector_type(4))) unsigned short ushx4;

__device__ inline unsigned short f2bf(float f) {
  unsigned u = __builtin_bit_cast(unsigned, f);
  u += 0x7fff + ((u >> 16) & 1);  // round-to-nearest-even
  return (unsigned short)(u >> 16);
}
__device__ inline float bf2f(unsigned short h) {
  unsigned u = ((unsigned)h) << 16;
  return __builtin_bit_cast(float, u);
}

// ---------------------------------------------------------------- cast X,W -> bf16
__global__ __launch_bounds__(256) void cast_kernel(const float* __restrict__ X,
                                                   const float* __restrict__ W,
                                                   unsigned short* __restrict__ Xb,
                                                   unsigned short* __restrict__ Wb) {
  const int NX4 = (S_DIM * K_DIM) / 4;  // multiple of 1024 -> block-uniform branch
#pragma unroll
  for (int i = 0; i < 4; ++i) {
    int g = blockIdx.x * 1024 + i * 256 + threadIdx.x;
    float4 v;
    unsigned short* dst;
    if (g < NX4) {
      v = ((const float4*)X)[g];
      dst = Xb + (size_t)g * 4;
    } else {
      int j = g - NX4;
      v = ((const float4*)W)[j];
      dst = Wb + (size_t)j * 4;
    }
    ushx4 o;
    o.x = f2bf(v.x); o.y = f2bf(v.y); o.z = f2bf(v.z); o.w = f2bf(v.w);
    *(ushx4*)dst = o;
  }
}

// ---------------------------------------------------------------- fused GEMM+sigmoid+rule-reduce
// Grid (8,64): block (bx,by) = s-rows by*128..+127 x rules bx*8..+7, looping
// rt=0..3 over 4 N-tiles of 128 cols (2 rules each). The per-thread (row,o)
// output positions are IDENTICAL across N-tiles, so the rule-sum accumulates
// in a 32-reg yacc -> partial slices 32->8 (saves ~50 MB of partial traffic),
// and X tiles are fetched by 8 column-groups instead of 32 (LLC reuse).
// Inner structure = R6 (BK=64, 16x16x32 MFMA, zero conflicts):
// - K-chunk XOR swizzle (row&7) at the GLOBAL address of global_load_lds.
// - Bias folded into acc init (exact); lambda via 1KB LDS side-buffer per rt.
// - NO min-waves bound (R2: forced occupancy spilled acc -> 417MB scratch).
// - fp8/MX rejected on numerics (threshold 0.46, bf16 absmax already 0.125).
__global__ __launch_bounds__(256) void gemm_kernel(const unsigned short* __restrict__ Xb,
                                                   const unsigned short* __restrict__ Wb,
                                                   const float* __restrict__ bias,
                                                   const float* __restrict__ lam,
                                                   unsigned short* __restrict__ partial) {
  __shared__ __align__(16) unsigned char smem[33792];
  unsigned short* Atile = (unsigned short*)smem;           // 128 rows x 64 k (16 KB)
  unsigned short* Btile = (unsigned short*)(smem + 16384); // 16 KB
  float* lamsh = (float*)(smem + 32768);                   // [128][2] (1 KB)

  const int t = threadIdx.x;
  const int lane = t & 63;
  const int w = t >> 6;
  const int wm = w & 1;        // wave row half (rows wm*64..+63)
  const int oh = w >> 1;       // o-column half (cols oh*32..+31 of each rule)
  const int quad = lane >> 4;  // 0..3
  const int l16 = lane & 15;
  const int gm0 = blockIdx.y * 128;

  float yacc[4][4][2];  // [mi][reg][ni] running rule-sum, 32 VGPR
#pragma unroll
  for (int mi = 0; mi < 4; ++mi)
#pragma unroll
    for (int reg = 0; reg < 4; ++reg) {
      yacc[mi][reg][0] = 0.f;
      yacc[mi][reg][1] = 0.f;
    }

  for (int rt = 0; rt < 4; ++rt) {
    const int gn0 = blockIdx.x * 512 + rt * 128;
    __syncthreads();  // previous rt's lamsh readers done before restaging
    {
      int row = t >> 1, rl = t & 1;
      lamsh[t] = lam[(size_t)(gm0 + row) * 64 + blockIdx.x * 8 + rt * 2 + rl];
    }

    // acc init = bias (C/D col = l16, same for all 4 regs) — exact fold
    floatx4 acc[4][2][2];
#pragma unroll
    for (int rh = 0; rh < 2; ++rh)
#pragma unroll
      for (int ni = 0; ni < 2; ++ni) {
        float bv = bias[gn0 + rh * 64 + oh * 32 + ni * 16 + l16];
#pragma unroll
        for (int mi = 0; mi < 4; ++mi)
          acc[mi][rh][ni] = (floatx4){bv, bv, bv, bv};
      }

    for (int k0 = 0; k0 < K_DIM; k0 += 64) {
      __syncthreads();
#pragma unroll
      for (int i = 0; i < 4; ++i) {
        int idx = i * 256 + t;       // 0..1023, lane-contiguous within each wave
        int row = idx >> 3;          // tile row 0..127
        int cc = idx & 7;            // LDS chunk slot within BK=64 (8 x 8 elems)
        int gcc = cc ^ (row & 7);    // global k-chunk held in this slot
        const unsigned short* ga = Xb + (size_t)(gm0 + row) * K_DIM + k0 + gcc * 8;
        const unsigned short* gb = Wb + (size_t)(gn0 + row) * K_DIM + k0 + gcc * 8;
        __builtin_amdgcn_global_load_lds(
            (const __attribute__((address_space(1))) void*)ga,
            (__attribute__((address_space(3))) void*)(Atile + idx * 8), 16, 0, 0);
        __builtin_amdgcn_global_load_lds(
            (const __attribute__((address_space(1))) void*)gb,
            (__attribute__((address_space(3))) void*)(Btile + idx * 8), 16, 0, 0);
      }
      __syncthreads();

      // two k-steps of 32; lane needs k = s*32 + quad*8 -> slot = (s*4+quad)^(row&7)
#pragma unroll
      for (int s = 0; s < 2; ++s) {
        bf16x8 af[4], bfr[2][2];
#pragma unroll
        for (int mi = 0; mi < 4; ++mi) {
          int row = wm * 64 + mi * 16 + l16;
          int cc = (s * 4 + quad) ^ (row & 7);
          af[mi] = *(const bf16x8*)(Atile + row * 64 + cc * 8);
        }
#pragma unroll
        for (int rh = 0; rh < 2; ++rh)
#pragma unroll
          for (int ni = 0; ni < 2; ++ni) {
            int row = rh * 64 + oh * 32 + ni * 16 + l16;
            int cc = (s * 4 + quad) ^ (row & 7);
            bfr[rh][ni] = *(const bf16x8*)(Btile + row * 64 + cc * 8);
          }
#pragma unroll
        for (int mi = 0; mi < 4; ++mi)
#pragma unroll
          for (int rh = 0; rh < 2; ++rh)
#pragma unroll
            for (int ni = 0; ni < 2; ++ni)
              acc[mi][rh][ni] = __builtin_amdgcn_mfma_f32_16x16x32_bf16(
                  af[mi], bfr[rh][ni], acc[mi][rh][ni], 0, 0, 0);
      }
    }

    // per-rt epilogue: rule-sum into yacc (registers only, no barriers)
#pragma unroll
    for (int mi = 0; mi < 4; ++mi) {
#pragma unroll
      for (int reg = 0; reg < 4; ++reg) {
        int row = wm * 64 + mi * 16 + quad * 4 + reg;
        float2 lv = *(const float2*)(lamsh + row * 2);
#pragma unroll
        for (int ni = 0; ni < 2; ++ni) {
          float h0 = 1.f / (1.f + __expf(-acc[mi][0][ni][reg]));
          float h1 = 1.f / (1.f + __expf(-acc[mi][1][ni][reg]));
          yacc[mi][reg][ni] += lv.x * h0 + lv.y * h1;
        }
      }
    }
  }

  // ---- final store: one 128x64 bf16 slice; layout [by][bx][128*64] so the
  // reduce reads 8 contiguous 16KB slices per s-tile ----
  unsigned short* pbase = partial + ((size_t)blockIdx.y * NSLICE + blockIdx.x) * (128 * O_DIM);
#pragma unroll
  for (int mi = 0; mi < 4; ++mi)
#pragma unroll
    for (int reg = 0; reg < 4; ++reg) {
      int row = wm * 64 + mi * 16 + quad * 4 + reg;
#pragma unroll
      for (int ni = 0; ni < 2; ++ni)
        pbase[(size_t)row * O_DIM + oh * 32 + ni * 16 + l16] = f2bf(yacc[mi][reg][ni]);
    }
}

// ---------------------------------------------------------------- final reduce over 8 N-slices
__global__ __launch_bounds__(256) void reduce_kernel(const unsigned short* __restrict__ partial,
                                                     float* __restrict__ Y) {
  int g = blockIdx.x * 256 + threadIdx.x;  // float4 group id
  int e = g * 4;
  int by = e >> 13;        // s-tile (8192 elems each)
  int local = e & 8191;
  const unsigned short* base = partial + (size_t)by * NSLICE * 8192 + local;
  float s0 = 0.f, s1 = 0.f, s2 = 0.f, s3 = 0.f;
#pragma unroll
  for (int c = 0; c < NSLICE; ++c) {
    ushx4 v = *(const ushx4*)(base + c * 8192);
    s0 += bf2f(v.x); s1 += bf2f(v.y); s2 += bf2f(v.z); s3 += bf2f(v.w);
  }
  ((float4*)Y)[g] = (float4){s0, s1, s2, s3};
}

extern "C" void kernel_launch(void* const* d_in, const int* in_sizes, int n_in,
                              void* d_out, int out_size, void* d_ws, size_t ws_size,
                              hipStream_t stream) {
  const float* X = (const float*)d_in[0];     // [8192,1024]
  const float* W = (const float*)d_in[1];     // [4096,1024]
  const float* b = (const float*)d_in[2];     // [4096]
  const float* lam = (const float*)d_in[3];   // [8192,64]
  float* Y = (float*)d_out;                   // [8192,64]

  unsigned short* Xb = (unsigned short*)d_ws;                       // 16 MB
  unsigned short* Wb = Xb + (size_t)S_DIM * K_DIM;                  // 8 MB
  unsigned short* partial = Wb + (size_t)RO_DIM * K_DIM;            // 8 slices x 1 MB = 8.4 MB

  int nCast = ((S_DIM + RO_DIM) * K_DIM / 4) / 1024;  // 3072 blocks
  cast_kernel<<<nCast, 256, 0, stream>>>(X, W, Xb, Wb);

  dim3 g(RO_DIM / 512, S_DIM / 128);  // (8, 64)
  gemm_kernel<<<g, 256, 0, stream>>>(Xb, Wb, b, lam, partial);

  reduce_kernel<<<SO / 1024, 256, 0, stream>>>(partial, Y);
}